// Round 5
// baseline (218.388 us; speedup 1.0000x reference)
//
#include <hip/hip_runtime.h>
#include <math.h>

#define NROWS 8192
#define DIN   60
#define DZ    16
#define NC    10

#define LOG2E 1.4426950408889634f

// K2 tiling: block = 512 thr (8 waves), 256 rows x 256 cols per block
#define RB  256
#define CJ  256
#define NRB (NROWS / RB)      // 32 row blocks
#define NCH (NROWS / CJ)      // 32 col chunks

typedef short bf16x8 __attribute__((ext_vector_type(8)));
typedef float f32x4  __attribute__((ext_vector_type(4)));

__device__ __forceinline__ unsigned int bfr(float f) {
    // bf16 bits, round-half-up
    return (__float_as_uint(f) + 0x8000u) >> 16;
}

// ---------------------------------------------------------------------------
// K1 (fused): z = fc2(fc1(x)); zb = bf16(z*sqrt(2*temp*log2e)) zero-padded to
// 32 K-slots; bbf_i = log2e*(temp*||z||^2 - theta/2); xT = bf16 transpose of
// x augmented with a ones-column (row 60) for the rowsum.
// 128 blocks x 64 thr so 128 CUs participate (was 32 -> latency-bound).
// ---------------------------------------------------------------------------
__global__ __launch_bounds__(64) void k1_all(
    const float* __restrict__ x,
    const float* __restrict__ w1, const float* __restrict__ b1,
    const float* __restrict__ w2, const float* __restrict__ b2,
    const float* __restrict__ temp_p, const float* __restrict__ theta_p,
    unsigned short* __restrict__ zb, float* __restrict__ bbf,
    unsigned short* __restrict__ xT)
{
    int i = blockIdx.x * 64 + threadIdx.x;

    float xr[DIN];
    const float4* xp = reinterpret_cast<const float4*>(x + (size_t)i * DIN);
    #pragma unroll
    for (int c = 0; c < 15; ++c) {
        float4 v = xp[c];
        xr[c*4+0] = v.x; xr[c*4+1] = v.y; xr[c*4+2] = v.z; xr[c*4+3] = v.w;
    }

    float n1[32];
    #pragma unroll
    for (int o = 0; o < 32; ++o) {
        float acc = b1[o];
        #pragma unroll
        for (int k = 0; k < DIN; ++k) acc = fmaf(w1[o*DIN+k], xr[k], acc);
        n1[o] = acc;
    }

    float z[DZ];
    float sq = 0.0f;
    #pragma unroll
    for (int u = 0; u < DZ; ++u) {
        float acc = b2[u];
        #pragma unroll
        for (int o = 0; o < 32; ++o) acc = fmaf(w2[u*32+o], n1[o], acc);
        z[u] = acc;
        sq = fmaf(acc, acc, sq);
    }

    float temp  = *temp_p;
    float theta = *theta_p;
    float s = sqrtf(2.0f * temp * LOG2E);

    unsigned int p[8];
    #pragma unroll
    for (int u = 0; u < 8; ++u) {
        unsigned int lo = bfr(z[2*u]   * s);
        unsigned int hi = bfr(z[2*u+1] * s);
        p[u] = lo | (hi << 16);
    }
    uint4* dst = reinterpret_cast<uint4*>(zb + (size_t)i * 32);
    dst[0] = make_uint4(p[0], p[1], p[2], p[3]);
    dst[1] = make_uint4(p[4], p[5], p[6], p[7]);
    dst[2] = make_uint4(0, 0, 0, 0);     // zero K-slots 16..31
    dst[3] = make_uint4(0, 0, 0, 0);

    bbf[i] = LOG2E * fmaf(temp, sq, -0.5f * theta);

    // transpose write (lane-contiguous in i -> coalesced 128B stores)
    #pragma unroll
    for (int c = 0; c < DIN; ++c)
        xT[(size_t)c * NROWS + i] = (unsigned short)bfr(xr[c]);
    xT[(size_t)60 * NROWS + i] = 0x3F80;  // 1.0
    xT[(size_t)61 * NROWS + i] = 0;
    xT[(size_t)62 * NROWS + i] = 0;
    xT[(size_t)63 * NROWS + i] = 0;
}

// ---------------------------------------------------------------------------
// K2: MFMA flash-style pairwise.
//   Per wave: 32 rows (2 i-tiles) x CJ cols. Swapped QK^T: S' = mfma(z_j, z_i)
//   -> C layout col = i (lane&15), row = j (4*(lane>>4)+reg).
//   sigmoid -> bf16 -> wave-private LDS (pitch 80B) -> A-frag for PV:
//   H[i][n] += P[i][j] @ xT-aug. Rowsum = col 60. Diag zeroed, k3 re-adds.
//   launch_bounds(512,8): VGPR<=64 so 8 waves/SIMD are schedulable;
//   grid 1024 blocks = 4 blocks/CU x 8 waves = full 32 waves/CU.
// ---------------------------------------------------------------------------
__global__ __launch_bounds__(512, 8) void k2_mfma(
    const unsigned short* __restrict__ zb, const float* __restrict__ bbf,
    const unsigned short* __restrict__ xT, const float* __restrict__ theta_p,
    float* __restrict__ hacc)   // [NCH][NROWS][64]
{
    __shared__ unsigned long long sP[8 * 320];   // 8 waves * 2560 B

    const int tid  = threadIdx.x;
    const int lane = tid & 63, wave = tid >> 6;
    const int q = lane & 15, g = lane >> 4;
    const int rb = blockIdx.x & (NRB - 1);
    const int ch = blockIdx.x >> 5;            // NRB == 32
    const int i0 = rb * RB + wave * 32;
    const int j0 = ch * CJ;

    bf16x8 zbi[2];
    float  bi[2];
    #pragma unroll
    for (int t = 0; t < 2; ++t) {
        zbi[t] = *reinterpret_cast<const bf16x8*>(zb + (size_t)(i0 + t*16 + q) * 32 + g*8);
        bi[t]  = bbf[i0 + t*16 + q];
    }
    const float nclamp = -(*theta_p) * LOG2E;
    const f32x4 z4 = {0.0f, 0.0f, 0.0f, 0.0f};

    f32x4 H[2][4];
    #pragma unroll
    for (int t = 0; t < 2; ++t)
        #pragma unroll
        for (int nt = 0; nt < 4; ++nt) H[t][nt] = z4;

    char* myP = reinterpret_cast<char*>(sP) + wave * 2560;

    for (int jp = 0; jp < CJ / 32; ++jp) {
        #pragma unroll
        for (int half = 0; half < 2; ++half) {
            const int gj = j0 + jp*32 + half*16;
            bf16x8 za = *reinterpret_cast<const bf16x8*>(zb + (size_t)(gj + q) * 32 + g*8);
            f32x4  bj = *reinterpret_cast<const f32x4*>(bbf + gj + 4*g);
            #pragma unroll
            for (int t = 0; t < 2; ++t) {
                f32x4 S = __builtin_amdgcn_mfma_f32_16x16x32_bf16(za, zbi[t], z4, 0, 0, 0);
                unsigned int ur[4];
                #pragma unroll
                for (int r = 0; r < 4; ++r) {
                    float n = (bi[t] + bj[r]) - S[r];
                    n = fmaxf(n, nclamp);
                    float P = __builtin_amdgcn_rcpf(1.0f + __builtin_amdgcn_exp2f(n));
                    if (i0 + t*16 == gj && q == 4*g + r) P = 0.0f;  // diag
                    ur[r] = __float_as_uint(P) + 0x8000u;
                }
                unsigned int pk0 = (ur[0] >> 16) | (ur[1] & 0xFFFF0000u);
                unsigned int pk1 = (ur[2] >> 16) | (ur[3] & 0xFFFF0000u);
                *reinterpret_cast<unsigned long long*>(
                    myP + t*1280 + q*80 + half*32 + g*8) =
                    ((unsigned long long)pk1 << 32) | pk0;
            }
        }
        // PV over this 32-j block (wave-private LDS: no barrier needed)
        const int jb = j0 + jp*32;
        bf16x8 pa[2];
        #pragma unroll
        for (int t = 0; t < 2; ++t)
            pa[t] = *reinterpret_cast<const bf16x8*>(myP + t*1280 + q*80 + g*16);
        #pragma unroll
        for (int nt = 0; nt < 4; ++nt) {
            bf16x8 xb = *reinterpret_cast<const bf16x8*>(
                xT + (size_t)(nt*16 + q) * NROWS + jb + g*8);
            H[0][nt] = __builtin_amdgcn_mfma_f32_16x16x32_bf16(pa[0], xb, H[0][nt], 0, 0, 0);
            H[1][nt] = __builtin_amdgcn_mfma_f32_16x16x32_bf16(pa[1], xb, H[1][nt], 0, 0, 0);
        }
    }

    // epilogue: C layout row = 4g+r (i within tile), col = q (n within tile)
    #pragma unroll
    for (int t = 0; t < 2; ++t)
        #pragma unroll
        for (int nt = 0; nt < 4; ++nt)
            #pragma unroll
            for (int r = 0; r < 4; ++r) {
                int row = i0 + t*16 + 4*g + r;
                hacc[((size_t)ch * NROWS + row) * 64 + nt*16 + q] = H[t][nt][r];
            }
}

// ---------------------------------------------------------------------------
// K3r: reduce [NCH][NROWS][64] partials into chunk 0 (in place).
//   512 blocks x 256 thr; thread owns one (row, float4-col): coalesced,
//   in-place safe, unroll-4 for memory-level parallelism.
// ---------------------------------------------------------------------------
__global__ __launch_bounds__(256) void k3_reduce(float* __restrict__ hacc)
{
    const int tid = threadIdx.x;
    const int r   = blockIdx.x * 16 + (tid >> 4);
    const int c   = (tid & 15) * 4;

    float4 s = make_float4(0.0f, 0.0f, 0.0f, 0.0f);
    #pragma unroll 4
    for (int ch = 0; ch < NCH; ++ch) {
        float4 v = *reinterpret_cast<const float4*>(
            hacc + ((size_t)ch * NROWS + r) * 64 + c);
        s.x += v.x; s.y += v.y; s.z += v.z; s.w += v.w;
    }
    *reinterpret_cast<float4*>(hacc + (size_t)r * 64 + c) = s;
}

// ---------------------------------------------------------------------------
// K3h: +x_i / +1 (exact diagonal), normalize, fc3, fc6, softmax
// ---------------------------------------------------------------------------
__global__ __launch_bounds__(64) void k3_head(
    const float* __restrict__ x,
    const float* __restrict__ w3, const float* __restrict__ b3,
    const float* __restrict__ w6, const float* __restrict__ b6,
    const float* __restrict__ hacc,
    float* __restrict__ out)
{
    int i = blockIdx.x * 64 + threadIdx.x;

    const float* hi = hacc + (size_t)i * 64;
    const float* xi = x + (size_t)i * DIN;

    float rd = __builtin_amdgcn_rcpf(hi[60] + 1.0f);

    float h[DIN];
    #pragma unroll
    for (int k = 0; k < DIN; ++k) h[k] = (hi[k] + xi[k]) * rd;

    float g[8];
    #pragma unroll
    for (int o = 0; o < 8; ++o) {
        float a = b3[o];
        #pragma unroll
        for (int k = 0; k < DIN; ++k) a = fmaf(w3[o*DIN+k], h[k], a);
        g[o] = a;
    }

    float l[NC];
    float m = -3.0e38f;
    #pragma unroll
    for (int c = 0; c < NC; ++c) {
        float a = b6[c];
        #pragma unroll
        for (int o = 0; o < 8; ++o) a = fmaf(w6[c*8+o], g[o], a);
        l[c] = a;
        m = fmaxf(m, a);
    }
    float e[NC];
    float sum = 0.0f;
    #pragma unroll
    for (int c = 0; c < NC; ++c) {
        e[c] = __builtin_amdgcn_exp2f((l[c] - m) * LOG2E);
        sum += e[c];
    }
    float rsum = __builtin_amdgcn_rcpf(sum);
    #pragma unroll
    for (int c = 0; c < NC; ++c) out[(size_t)i * NC + c] = e[c] * rsum;
}

// ---------------------------------------------------------------------------
extern "C" void kernel_launch(void* const* d_in, const int* in_sizes, int n_in,
                              void* d_out, int out_size, void* d_ws, size_t ws_size,
                              hipStream_t stream)
{
    const float* x     = (const float*)d_in[0];
    const float* w1    = (const float*)d_in[1];
    const float* b1    = (const float*)d_in[2];
    const float* w2    = (const float*)d_in[3];
    const float* b2    = (const float*)d_in[4];
    const float* w3    = (const float*)d_in[5];
    const float* b3    = (const float*)d_in[6];
    const float* w6    = (const float*)d_in[7];
    const float* b6    = (const float*)d_in[8];
    const float* temp  = (const float*)d_in[9];
    const float* theta = (const float*)d_in[10];
    float* out = (float*)d_out;

    // ws carve-up: 0.5 + 0.03 + 1 + 64 MB = 65.5 MB (ws >= 67.6 MB proven r2/r3)
    char* p = (char*)d_ws;
    unsigned short* zbuf = (unsigned short*)p;  p += (size_t)NROWS * 32 * 2;   // 512 KB
    float*          bbf  = (float*)p;           p += (size_t)NROWS * 4;        // 32 KB
    unsigned short* xT   = (unsigned short*)p;  p += (size_t)64 * NROWS * 2;   // 1 MB
    float*          hbuf = (float*)p;           // [NCH][NROWS][64] = 64 MB

    k1_all  <<<NROWS / 64, 64, 0, stream>>>(x, w1, b1, w2, b2, temp, theta, zbuf, bbf, xT);
    k2_mfma <<<NRB * NCH, 512, 0, stream>>>(zbuf, bbf, xT, theta, hbuf);
    k3_reduce<<<NROWS / 16, 256, 0, stream>>>(hbuf);
    k3_head <<<NROWS / 64, 64, 0, stream>>>(x, w3, b3, w6, b6, hbuf, out);
}

// Round 7
// 181.826 us; speedup vs baseline: 1.2011x; 1.2011x over previous
//
#include <hip/hip_runtime.h>
#include <math.h>

#define NROWS 8192
#define DIN   60
#define DZ    16
#define NC    10

#define LOG2E 1.4426950408889634f

// K2 tiling: block = 512 thr (8 waves), each wave owns 32 rows (2 i-tiles).
// RB=256 rows/block, CJ=256 cols/chunk -> grid 32*32 = 1024 blocks
// (waves/CU when fully resident = NCH = 32).
#define RB  256
#define CJ  256
#define NRB (NROWS / RB)      // 32 row blocks
#define NCH (NROWS / CJ)      // 32 col chunks

typedef short bf16x8 __attribute__((ext_vector_type(8)));
typedef float f32x4  __attribute__((ext_vector_type(4)));

__device__ __forceinline__ unsigned int bfr(float f) {
    // bf16 bits, round-half-up
    return (__float_as_uint(f) + 0x8000u) >> 16;
}

// ---------------------------------------------------------------------------
// K1 (fused): z = fc2(fc1(x)); zb = bf16(z*sqrt(2*temp*log2e)) zero-padded to
// 32 K-slots; bbf_i = log2e*(temp*||z||^2 - theta/2); xT = bf16 transpose of
// x augmented with a ones-column (row 60) for the rowsum.
// ---------------------------------------------------------------------------
__global__ __launch_bounds__(64) void k1_all(
    const float* __restrict__ x,
    const float* __restrict__ w1, const float* __restrict__ b1,
    const float* __restrict__ w2, const float* __restrict__ b2,
    const float* __restrict__ temp_p, const float* __restrict__ theta_p,
    unsigned short* __restrict__ zb, float* __restrict__ bbf,
    unsigned short* __restrict__ xT)
{
    int i = blockIdx.x * 64 + threadIdx.x;

    float xr[DIN];
    const float4* xp = reinterpret_cast<const float4*>(x + (size_t)i * DIN);
    #pragma unroll
    for (int c = 0; c < 15; ++c) {
        float4 v = xp[c];
        xr[c*4+0] = v.x; xr[c*4+1] = v.y; xr[c*4+2] = v.z; xr[c*4+3] = v.w;
    }

    float n1[32];
    #pragma unroll
    for (int o = 0; o < 32; ++o) {
        float acc = b1[o];
        #pragma unroll
        for (int k = 0; k < DIN; ++k) acc = fmaf(w1[o*DIN+k], xr[k], acc);
        n1[o] = acc;
    }

    float z[DZ];
    float sq = 0.0f;
    #pragma unroll
    for (int u = 0; u < DZ; ++u) {
        float acc = b2[u];
        #pragma unroll
        for (int o = 0; o < 32; ++o) acc = fmaf(w2[u*32+o], n1[o], acc);
        z[u] = acc;
        sq = fmaf(acc, acc, sq);
    }

    float temp  = *temp_p;
    float theta = *theta_p;
    float s = sqrtf(2.0f * temp * LOG2E);

    unsigned int p[8];
    #pragma unroll
    for (int u = 0; u < 8; ++u) {
        unsigned int lo = bfr(z[2*u]   * s);
        unsigned int hi = bfr(z[2*u+1] * s);
        p[u] = lo | (hi << 16);
    }
    uint4* dst = reinterpret_cast<uint4*>(zb + (size_t)i * 32);
    dst[0] = make_uint4(p[0], p[1], p[2], p[3]);
    dst[1] = make_uint4(p[4], p[5], p[6], p[7]);
    dst[2] = make_uint4(0, 0, 0, 0);     // zero K-slots 16..31
    dst[3] = make_uint4(0, 0, 0, 0);

    bbf[i] = LOG2E * fmaf(temp, sq, -0.5f * theta);

    // transpose write (lane-contiguous in i -> coalesced stores)
    #pragma unroll
    for (int c = 0; c < DIN; ++c)
        xT[(size_t)c * NROWS + i] = (unsigned short)bfr(xr[c]);
    xT[(size_t)60 * NROWS + i] = 0x3F80;  // 1.0
    xT[(size_t)61 * NROWS + i] = 0;
    xT[(size_t)62 * NROWS + i] = 0;
    xT[(size_t)63 * NROWS + i] = 0;
}

// ---------------------------------------------------------------------------
// K2: MFMA flash-style pairwise (round-4 proven structure, hardened).
//   Per wave: 32 rows (2 i-tiles) x CJ cols. Swapped QK^T: S' = mfma(z_j,z_i)
//   -> C layout col = i (lane&15), row = j (4*(lane>>4)+reg).
//   sigmoid -> bf16 packed -> LDS (ull-typed both ways, pitch 80B) ->
//   A-frag for PV: H[i][n] += P[i][j] @ xT-aug. Rowsum = col 60.
//   Diag zeroed here; k3 re-adds +x_i/+1 exactly in fp32.
//   __syncthreads() between LDS write and read phases: rounds 4-6 used
//   type-punned unfenced LDS (strict-aliasing UB); r6 failed post-timing
//   nondeterministically. Same-type + barrier makes ordering airtight.
// ---------------------------------------------------------------------------
__global__ __launch_bounds__(512, 4) void k2_mfma(
    const unsigned short* __restrict__ zb, const float* __restrict__ bbf,
    const unsigned short* __restrict__ xT, const float* __restrict__ theta_p,
    float* __restrict__ hacc)   // [NCH][NROWS][64]
{
    __shared__ unsigned long long sP[8 * 320];   // 8 waves * 2560 B

    const int tid  = threadIdx.x;
    const int lane = tid & 63, wave = tid >> 6;
    const int q = lane & 15, g = lane >> 4;
    const int rb = blockIdx.x & (NRB - 1);
    const int ch = blockIdx.x >> 5;            // NRB == 32
    const int i0 = rb * RB + wave * 32;
    const int j0 = ch * CJ;

    bf16x8 zbi[2];
    float  bi[2];
    #pragma unroll
    for (int t = 0; t < 2; ++t) {
        zbi[t] = *reinterpret_cast<const bf16x8*>(zb + (size_t)(i0 + t*16 + q) * 32 + g*8);
        bi[t]  = bbf[i0 + t*16 + q];
    }
    const float nclamp = -(*theta_p) * LOG2E;
    const f32x4 z4 = {0.0f, 0.0f, 0.0f, 0.0f};

    f32x4 H[2][4];
    #pragma unroll
    for (int t = 0; t < 2; ++t)
        #pragma unroll
        for (int nt = 0; nt < 4; ++nt) H[t][nt] = z4;

    unsigned long long* myP = sP + wave * 320;   // 320 ull = 2560 B per wave

    for (int jp = 0; jp < CJ / 32; ++jp) {
        // ---- phase 1: QK^T + sigmoid + pack -> LDS (ull writes) ----
        #pragma unroll
        for (int half = 0; half < 2; ++half) {
            const int gj = j0 + jp*32 + half*16;
            bf16x8 za = *reinterpret_cast<const bf16x8*>(zb + (size_t)(gj + q) * 32 + g*8);
            f32x4  bj = *reinterpret_cast<const f32x4*>(bbf + gj + 4*g);
            #pragma unroll
            for (int t = 0; t < 2; ++t) {
                f32x4 S = __builtin_amdgcn_mfma_f32_16x16x32_bf16(za, zbi[t], z4, 0, 0, 0);
                unsigned int ur[4];
                #pragma unroll
                for (int r = 0; r < 4; ++r) {
                    float n = (bi[t] + bj[r]) - S[r];
                    n = fmaxf(n, nclamp);
                    float P = __builtin_amdgcn_rcpf(1.0f + __builtin_amdgcn_exp2f(n));
                    if (i0 + t*16 == gj && q == 4*g + r) P = 0.0f;  // diag
                    ur[r] = __float_as_uint(P) + 0x8000u;
                }
                unsigned int pk0 = (ur[0] >> 16) | (ur[1] & 0xFFFF0000u);
                unsigned int pk1 = (ur[2] >> 16) | (ur[3] & 0xFFFF0000u);
                // byte layout: t*1280 + q*80 + half*32 + g*8  (ull index /8)
                myP[t*160 + q*10 + half*4 + g] =
                    ((unsigned long long)pk1 << 32) | pk0;
            }
        }
        __syncthreads();   // LDS writes visible + ordered before reads

        // ---- phase 2: LDS -> A-frag (ull reads), PV MFMA ----
        const int jb = j0 + jp*32;
        bf16x8 pa[2];
        #pragma unroll
        for (int t = 0; t < 2; ++t) {
            union { unsigned long long u[2]; bf16x8 v; } pu;
            // byte layout: t*1280 + q*80 + g*16
            pu.u[0] = myP[t*160 + q*10 + g*2];
            pu.u[1] = myP[t*160 + q*10 + g*2 + 1];
            pa[t] = pu.v;
        }
        #pragma unroll
        for (int nt = 0; nt < 4; ++nt) {
            bf16x8 xb = *reinterpret_cast<const bf16x8*>(
                xT + (size_t)(nt*16 + q) * NROWS + jb + g*8);
            H[0][nt] = __builtin_amdgcn_mfma_f32_16x16x32_bf16(pa[0], xb, H[0][nt], 0, 0, 0);
            H[1][nt] = __builtin_amdgcn_mfma_f32_16x16x32_bf16(pa[1], xb, H[1][nt], 0, 0, 0);
        }
        __syncthreads();   // reads done before next iteration overwrites
    }

    // epilogue: C layout row = 4g+r (i within tile), col = q (n within tile)
    #pragma unroll
    for (int t = 0; t < 2; ++t)
        #pragma unroll
        for (int nt = 0; nt < 4; ++nt)
            #pragma unroll
            for (int r = 0; r < 4; ++r) {
                int row = i0 + t*16 + 4*g + r;
                hacc[((size_t)ch * NROWS + row) * 64 + nt*16 + q] = H[t][nt][r];
            }
}

// ---------------------------------------------------------------------------
// K3r: reduce [NCH][NROWS][64] partials into chunk 0 (in place).
//   512 blocks x 256 thr; thread owns one (row, float4-col): coalesced,
//   in-place safe (each thread reads ch=0 before overwriting it),
//   32 independent loads per thread for MLP.
// ---------------------------------------------------------------------------
__global__ __launch_bounds__(256) void k3_reduce(float* __restrict__ hacc)
{
    const int tid = threadIdx.x;
    const int r   = blockIdx.x * 16 + (tid >> 4);
    const int c   = (tid & 15) * 4;

    float4 s = make_float4(0.0f, 0.0f, 0.0f, 0.0f);
    #pragma unroll 8
    for (int ch = 0; ch < NCH; ++ch) {
        float4 v = *reinterpret_cast<const float4*>(
            hacc + ((size_t)ch * NROWS + r) * 64 + c);
        s.x += v.x; s.y += v.y; s.z += v.z; s.w += v.w;
    }
    *reinterpret_cast<float4*>(hacc + (size_t)r * 64 + c) = s;
}

// ---------------------------------------------------------------------------
// K3h: +x_i / +1 (exact diagonal), normalize, fc3, fc6, softmax
// ---------------------------------------------------------------------------
__global__ __launch_bounds__(64) void k3_head(
    const float* __restrict__ x,
    const float* __restrict__ w3, const float* __restrict__ b3,
    const float* __restrict__ w6, const float* __restrict__ b6,
    const float* __restrict__ hacc,
    float* __restrict__ out)
{
    int i = blockIdx.x * 64 + threadIdx.x;

    const float* hi = hacc + (size_t)i * 64;
    const float* xi = x + (size_t)i * DIN;

    float rd = __builtin_amdgcn_rcpf(hi[60] + 1.0f);

    float h[DIN];
    #pragma unroll
    for (int k = 0; k < DIN; ++k) h[k] = (hi[k] + xi[k]) * rd;

    float g[8];
    #pragma unroll
    for (int o = 0; o < 8; ++o) {
        float a = b3[o];
        #pragma unroll
        for (int k = 0; k < DIN; ++k) a = fmaf(w3[o*DIN+k], h[k], a);
        g[o] = a;
    }

    float l[NC];
    float m = -3.0e38f;
    #pragma unroll
    for (int c = 0; c < NC; ++c) {
        float a = b6[c];
        #pragma unroll
        for (int o = 0; o < 8; ++o) a = fmaf(w6[c*8+o], g[o], a);
        l[c] = a;
        m = fmaxf(m, a);
    }
    float e[NC];
    float sum = 0.0f;
    #pragma unroll
    for (int c = 0; c < NC; ++c) {
        e[c] = __builtin_amdgcn_exp2f((l[c] - m) * LOG2E);
        sum += e[c];
    }
    float rsum = __builtin_amdgcn_rcpf(sum);
    #pragma unroll
    for (int c = 0; c < NC; ++c) out[(size_t)i * NC + c] = e[c] * rsum;
}

// ---------------------------------------------------------------------------
extern "C" void kernel_launch(void* const* d_in, const int* in_sizes, int n_in,
                              void* d_out, int out_size, void* d_ws, size_t ws_size,
                              hipStream_t stream)
{
    const float* x     = (const float*)d_in[0];
    const float* w1    = (const float*)d_in[1];
    const float* b1    = (const float*)d_in[2];
    const float* w2    = (const float*)d_in[3];
    const float* b2    = (const float*)d_in[4];
    const float* w3    = (const float*)d_in[5];
    const float* b3    = (const float*)d_in[6];
    const float* w6    = (const float*)d_in[7];
    const float* b6    = (const float*)d_in[8];
    const float* temp  = (const float*)d_in[9];
    const float* theta = (const float*)d_in[10];
    float* out = (float*)d_out;

    // ws carve-up: 0.5 + 0.03 + 1 + 64 MiB = 65.6 MiB (ws >= 67.7 MB proven r2/r3)
    char* p = (char*)d_ws;
    unsigned short* zbuf = (unsigned short*)p;  p += (size_t)NROWS * 32 * 2;   // 512 KiB
    float*          bbf  = (float*)p;           p += (size_t)NROWS * 4;        // 32 KiB
    unsigned short* xT   = (unsigned short*)p;  p += (size_t)64 * NROWS * 2;   // 1 MiB
    float*          hbuf = (float*)p;           // [NCH][NROWS][64] = 64 MiB

    k1_all  <<<NROWS / 64, 64, 0, stream>>>(x, w1, b1, w2, b2, temp, theta, zbuf, bbf, xT);
    k2_mfma <<<NRB * NCH, 512, 0, stream>>>(zbuf, bbf, xT, theta, hbuf);
    k3_reduce<<<NROWS / 16, 256, 0, stream>>>(hbuf);
    k3_head <<<NROWS / 64, 64, 0, stream>>>(x, w3, b3, w6, b6, hbuf, out);
}

// Round 8
// 173.454 us; speedup vs baseline: 1.2590x; 1.0483x over previous
//
#include <hip/hip_runtime.h>
#include <math.h>

#define NROWS 8192
#define DIN   60
#define DZ    16
#define NC    10

#define LOG2E 1.4426950408889634f

// K2 tiling: block = 256 thr (4 waves), each wave owns 32 rows (2 i-tiles).
// RB=128 rows/block, CJ=512 cols/chunk -> grid 64*16 = 1024 blocks.
#define RB    128
#define CJ    512
#define NRB   (NROWS / RB)    // 64 row blocks
#define NCH   (NROWS / CJ)    // 16 col chunks
#define WAVES 4

typedef short bf16x8 __attribute__((ext_vector_type(8)));
typedef float f32x4  __attribute__((ext_vector_type(4)));

__device__ __forceinline__ unsigned int bfr(float f) {
    // bf16 bits, round-half-up
    return (__float_as_uint(f) + 0x8000u) >> 16;
}

// ---------------------------------------------------------------------------
// K1 (fused): z = fc2(fc1(x)); zb = bf16(z*sqrt(2*temp*log2e)) zero-padded to
// 32 K-slots; bbf_i = log2e*(temp*||z||^2 - theta/2); xT = bf16 transpose of
// x augmented with a ones-column (row 60) for the rowsum.
// ---------------------------------------------------------------------------
__global__ __launch_bounds__(64) void k1_all(
    const float* __restrict__ x,
    const float* __restrict__ w1, const float* __restrict__ b1,
    const float* __restrict__ w2, const float* __restrict__ b2,
    const float* __restrict__ temp_p, const float* __restrict__ theta_p,
    unsigned short* __restrict__ zb, float* __restrict__ bbf,
    unsigned short* __restrict__ xT)
{
    int i = blockIdx.x * 64 + threadIdx.x;

    float xr[DIN];
    const float4* xp = reinterpret_cast<const float4*>(x + (size_t)i * DIN);
    #pragma unroll
    for (int c = 0; c < 15; ++c) {
        float4 v = xp[c];
        xr[c*4+0] = v.x; xr[c*4+1] = v.y; xr[c*4+2] = v.z; xr[c*4+3] = v.w;
    }

    float n1[32];
    #pragma unroll
    for (int o = 0; o < 32; ++o) {
        float acc = b1[o];
        #pragma unroll
        for (int k = 0; k < DIN; ++k) acc = fmaf(w1[o*DIN+k], xr[k], acc);
        n1[o] = acc;
    }

    float z[DZ];
    float sq = 0.0f;
    #pragma unroll
    for (int u = 0; u < DZ; ++u) {
        float acc = b2[u];
        #pragma unroll
        for (int o = 0; o < 32; ++o) acc = fmaf(w2[u*32+o], n1[o], acc);
        z[u] = acc;
        sq = fmaf(acc, acc, sq);
    }

    float temp  = *temp_p;
    float theta = *theta_p;
    float s = sqrtf(2.0f * temp * LOG2E);

    unsigned int p[8];
    #pragma unroll
    for (int u = 0; u < 8; ++u) {
        unsigned int lo = bfr(z[2*u]   * s);
        unsigned int hi = bfr(z[2*u+1] * s);
        p[u] = lo | (hi << 16);
    }
    uint4* dst = reinterpret_cast<uint4*>(zb + (size_t)i * 32);
    dst[0] = make_uint4(p[0], p[1], p[2], p[3]);
    dst[1] = make_uint4(p[4], p[5], p[6], p[7]);
    dst[2] = make_uint4(0, 0, 0, 0);     // zero K-slots 16..31
    dst[3] = make_uint4(0, 0, 0, 0);

    bbf[i] = LOG2E * fmaf(temp, sq, -0.5f * theta);

    // transpose write (lane-contiguous in i -> coalesced stores)
    #pragma unroll
    for (int c = 0; c < DIN; ++c)
        xT[(size_t)c * NROWS + i] = (unsigned short)bfr(xr[c]);
    xT[(size_t)60 * NROWS + i] = 0x3F80;  // 1.0
    xT[(size_t)61 * NROWS + i] = 0;
    xT[(size_t)62 * NROWS + i] = 0;
    xT[(size_t)63 * NROWS + i] = 0;
}

// ---------------------------------------------------------------------------
// K2: MFMA flash-style pairwise (r4/r7 proven math, independent-wave version).
//   Per wave: 32 rows (2 i-tiles) x CJ cols. Swapped QK^T: S' = mfma(z_j,z_i)
//   -> C layout col = i (lane&15), row = j (4*(lane>>4)+reg).
//   sigmoid -> bf16 packed -> wave-private LDS (ull-typed BOTH ways so the
//   compiler sees the dependence; __threadfence_block = lgkmcnt fence, no
//   block-wide convoy like r7's __syncthreads) -> A-frag for PV.
//   Epilogue: H stored in NATURAL register layout, flat
//   [ch][rb][wave][slot=t*16+nt*4+r][lane] -> 32 stores x 256 B contiguous.
//   k3_reduce de-swizzles. Diag zeroed here; k3 re-adds +x_i/+1 in fp32.
// ---------------------------------------------------------------------------
__global__ __launch_bounds__(256, 4) void k2_mfma(
    const unsigned short* __restrict__ zb, const float* __restrict__ bbf,
    const unsigned short* __restrict__ xT, const float* __restrict__ theta_p,
    float* __restrict__ hacc)   // [NCH][NRB][WAVES][32][64] floats
{
    __shared__ unsigned long long sP[WAVES * 320];   // 2560 B per wave

    const int tid  = threadIdx.x;
    const int lane = tid & 63, wave = tid >> 6;
    const int q = lane & 15, g = lane >> 4;
    const int rb = blockIdx.x & (NRB - 1);
    const int ch = blockIdx.x >> 6;            // NRB == 64
    const int i0 = rb * RB + wave * 32;
    const int j0 = ch * CJ;

    bf16x8 zbi[2];
    float  bi[2];
    #pragma unroll
    for (int t = 0; t < 2; ++t) {
        zbi[t] = *reinterpret_cast<const bf16x8*>(zb + (size_t)(i0 + t*16 + q) * 32 + g*8);
        bi[t]  = bbf[i0 + t*16 + q];
    }
    const float nclamp = -(*theta_p) * LOG2E;
    const f32x4 z4 = {0.0f, 0.0f, 0.0f, 0.0f};

    f32x4 H[2][4];
    #pragma unroll
    for (int t = 0; t < 2; ++t)
        #pragma unroll
        for (int nt = 0; nt < 4; ++nt) H[t][nt] = z4;

    unsigned long long* myP = sP + wave * 320;

    for (int jp = 0; jp < CJ / 32; ++jp) {
        // ---- phase 1: QK^T + sigmoid + pack -> LDS (ull writes) ----
        #pragma unroll
        for (int half = 0; half < 2; ++half) {
            const int gj = j0 + jp*32 + half*16;
            bf16x8 za = *reinterpret_cast<const bf16x8*>(zb + (size_t)(gj + q) * 32 + g*8);
            f32x4  bj = *reinterpret_cast<const f32x4*>(bbf + gj + 4*g);
            #pragma unroll
            for (int t = 0; t < 2; ++t) {
                f32x4 S = __builtin_amdgcn_mfma_f32_16x16x32_bf16(za, zbi[t], z4, 0, 0, 0);
                unsigned int ur[4];
                #pragma unroll
                for (int r = 0; r < 4; ++r) {
                    float n = (bi[t] + bj[r]) - S[r];
                    n = fmaxf(n, nclamp);
                    float P = __builtin_amdgcn_rcpf(1.0f + __builtin_amdgcn_exp2f(n));
                    if (i0 + t*16 == gj && q == 4*g + r) P = 0.0f;  // diag
                    ur[r] = __float_as_uint(P) + 0x8000u;
                }
                unsigned int pk0 = (ur[0] >> 16) | (ur[1] & 0xFFFF0000u);
                unsigned int pk1 = (ur[2] >> 16) | (ur[3] & 0xFFFF0000u);
                // byte layout: t*1280 + q*80 + half*32 + g*8  (ull index /8)
                myP[t*160 + q*10 + half*4 + g] =
                    ((unsigned long long)pk1 << 32) | pk0;
            }
        }
        __threadfence_block();   // lgkmcnt fence: LDS writes complete (wave-local)

        // ---- phase 2: LDS -> A-frag (ull reads), PV MFMA ----
        const int jb = j0 + jp*32;
        bf16x8 pa[2];
        #pragma unroll
        for (int t = 0; t < 2; ++t) {
            union { unsigned long long u[2]; bf16x8 v; } pu;
            pu.u[0] = myP[t*160 + q*10 + g*2];      // byte: t*1280 + q*80 + g*16
            pu.u[1] = myP[t*160 + q*10 + g*2 + 1];
            pa[t] = pu.v;
        }
        #pragma unroll
        for (int nt = 0; nt < 4; ++nt) {
            bf16x8 xb = *reinterpret_cast<const bf16x8*>(
                xT + (size_t)(nt*16 + q) * NROWS + jb + g*8);
            H[0][nt] = __builtin_amdgcn_mfma_f32_16x16x32_bf16(pa[0], xb, H[0][nt], 0, 0, 0);
            H[1][nt] = __builtin_amdgcn_mfma_f32_16x16x32_bf16(pa[1], xb, H[1][nt], 0, 0, 0);
        }
    }

    // epilogue: natural-layout flat store, each inst = 256 B contiguous
    float* regout = hacc + (((size_t)(ch * NRB + rb) * WAVES + wave) * 32) * 64;
    #pragma unroll
    for (int t = 0; t < 2; ++t)
        #pragma unroll
        for (int nt = 0; nt < 4; ++nt)
            #pragma unroll
            for (int r = 0; r < 4; ++r)
                regout[(t*16 + nt*4 + r) * 64 + lane] = H[t][nt][r];
}

// ---------------------------------------------------------------------------
// K3r: reduce flat partials [NCH][2 MiB] -> de-swizzle -> hfin[8192][64].
//   Thread owns one float4 of the flat layout: 16 coalesced strided loads,
//   one scattered float4 write (2 MiB total, L2-absorbed).
//   Decode: f = 4*T; lane=f&63; slot=(f>>6)&31; wv=(f>>11)&3; rb=f>>13;
//   i = rb*128 + wv*32 + (slot>>4)*16 + (lane>>4)*4 + (slot&3);
//   c0 = ((slot>>2)&3)*16 + (lane&15).
// ---------------------------------------------------------------------------
#define CHSTRIDE4 (NROWS * 16)   // float4s per chunk (= 2 MiB / 16 B)

__global__ __launch_bounds__(256) void k3_reduce(
    const float* __restrict__ hacc, float* __restrict__ hfin)
{
    const int T = blockIdx.x * 256 + threadIdx.x;   // float4 index in chunk

    const float4* src = reinterpret_cast<const float4*>(hacc) + T;
    float4 s = make_float4(0.0f, 0.0f, 0.0f, 0.0f);
    #pragma unroll 8
    for (int ch = 0; ch < NCH; ++ch) {
        float4 v = src[(size_t)ch * CHSTRIDE4];
        s.x += v.x; s.y += v.y; s.z += v.z; s.w += v.w;
    }

    const int f    = T * 4;
    const int lane = f & 63;
    const int slot = (f >> 6) & 31;
    const int wv   = (f >> 11) & 3;
    const int rb   = f >> 13;
    const int i  = rb * RB + wv * 32 + ((slot >> 4) * 16) + ((lane >> 4) * 4) + (slot & 3);
    const int c0 = ((slot >> 2) & 3) * 16 + (lane & 15);

    *reinterpret_cast<float4*>(hfin + (size_t)i * 64 + c0) = s;
}

// ---------------------------------------------------------------------------
// K3h: +x_i / +1 (exact diagonal), normalize, fc3, fc6, softmax
// ---------------------------------------------------------------------------
__global__ __launch_bounds__(64) void k3_head(
    const float* __restrict__ x,
    const float* __restrict__ w3, const float* __restrict__ b3,
    const float* __restrict__ w6, const float* __restrict__ b6,
    const float* __restrict__ hfin,
    float* __restrict__ out)
{
    int i = blockIdx.x * 64 + threadIdx.x;

    const float* hi = hfin + (size_t)i * 64;
    const float* xi = x + (size_t)i * DIN;

    float rd = __builtin_amdgcn_rcpf(hi[60] + 1.0f);

    float h[DIN];
    #pragma unroll
    for (int k = 0; k < DIN; ++k) h[k] = (hi[k] + xi[k]) * rd;

    float g[8];
    #pragma unroll
    for (int o = 0; o < 8; ++o) {
        float a = b3[o];
        #pragma unroll
        for (int k = 0; k < DIN; ++k) a = fmaf(w3[o*DIN+k], h[k], a);
        g[o] = a;
    }

    float l[NC];
    float m = -3.0e38f;
    #pragma unroll
    for (int c = 0; c < NC; ++c) {
        float a = b6[c];
        #pragma unroll
        for (int o = 0; o < 8; ++o) a = fmaf(w6[c*8+o], g[o], a);
        l[c] = a;
        m = fmaxf(m, a);
    }
    float e[NC];
    float sum = 0.0f;
    #pragma unroll
    for (int c = 0; c < NC; ++c) {
        e[c] = __builtin_amdgcn_exp2f((l[c] - m) * LOG2E);
        sum += e[c];
    }
    float rsum = __builtin_amdgcn_rcpf(sum);
    #pragma unroll
    for (int c = 0; c < NC; ++c) out[(size_t)i * NC + c] = e[c] * rsum;
}

// ---------------------------------------------------------------------------
extern "C" void kernel_launch(void* const* d_in, const int* in_sizes, int n_in,
                              void* d_out, int out_size, void* d_ws, size_t ws_size,
                              hipStream_t stream)
{
    const float* x     = (const float*)d_in[0];
    const float* w1    = (const float*)d_in[1];
    const float* b1    = (const float*)d_in[2];
    const float* w2    = (const float*)d_in[3];
    const float* b2    = (const float*)d_in[4];
    const float* w3    = (const float*)d_in[5];
    const float* b3    = (const float*)d_in[6];
    const float* w6    = (const float*)d_in[7];
    const float* b6    = (const float*)d_in[8];
    const float* temp  = (const float*)d_in[9];
    const float* theta = (const float*)d_in[10];
    float* out = (float*)d_out;

    // ws carve-up: 0.5 + 0.03 + 1 + 32 + 2 MiB = 35.6 MiB (ws >= 67 MB proven)
    char* p = (char*)d_ws;
    unsigned short* zbuf = (unsigned short*)p;  p += (size_t)NROWS * 32 * 2;      // 512 KiB
    float*          bbf  = (float*)p;           p += (size_t)NROWS * 4;           // 32 KiB
    unsigned short* xT   = (unsigned short*)p;  p += (size_t)64 * NROWS * 2;      // 1 MiB
    float*          hacc = (float*)p;           p += (size_t)NCH * NROWS * 64 * 4;// 32 MiB
    float*          hfin = (float*)p;           // [NROWS][64] = 2 MiB

    k1_all   <<<NROWS / 64, 64, 0, stream>>>(x, w1, b1, w2, b2, temp, theta, zbuf, bbf, xT);
    k2_mfma  <<<NRB * NCH, 256, 0, stream>>>(zbuf, bbf, xT, theta, hacc);
    k3_reduce<<<NROWS * 16 / 256, 256, 0, stream>>>(hacc, hfin);
    k3_head  <<<NROWS / 64, 64, 0, stream>>>(x, w3, b3, w6, b6, hfin, out);
}